// Round 3
// baseline (8313.620 us; speedup 1.0000x reference)
//
#include <hip/hip_runtime.h>

#define NMODES   64
#define NOFF     2016     // 64*63/2
#define BATCHN   1024
#define NEVAL    200
#define TAYLOR_K 12
#define SQUARINGS 10

#define WS 4           // waves per block (K-split factor)
#define KC (64/WS)     // columns per wave = 16

typedef float v2f __attribute__((ext_vector_type(2)));

// ---------------------------------------------------------------------------
// ws layout (bytes):
//   X    @ 0        : 64*64 double2 = 65536   (X = i*H/2^s)
//   Ta   @ 65536    : 65536                   (ping)
//   Tb   @ 131072   : 65536                   (pong)
//   W    @ 196608   : 64*128 double2 = 131072 (Gauss-Jordan augmented)
//   Binv @ 327680   : 65536
//   T2c  @ 393216   : 64*64 float2 = 32768    (final fp32 T2)
// ---------------------------------------------------------------------------

__global__ void build_kernel(const float* __restrict__ params,
                             double2* __restrict__ X, double2* __restrict__ T,
                             double inv2s)
{
    int t = blockIdx.x * 256 + threadIdx.x;
    if (t >= NMODES * NMODES) return;
    int r = t >> 6, c = t & 63;
    double hre, him;
    if (r < c) {
        int idx = r * 63 - (r * (r - 1)) / 2 + (c - r - 1);
        hre = (double)params[idx];
        him = (double)params[NOFF + idx];
    } else if (r > c) {
        int idx = c * 63 - (c * (c - 1)) / 2 + (r - c - 1);
        hre = (double)params[idx];
        him = -(double)params[NOFF + idx];
    } else {
        him = 0.0;
        if (r < 63) {
            hre = (double)params[2 * NOFF + r];
        } else {
            double s = 0.0;
            for (int q = 0; q < 63; ++q) s += (double)params[2 * NOFF + q];
            hre = -s;
        }
    }
    X[t] = make_double2(-him * inv2s, hre * inv2s);
    T[t] = make_double2((r == c) ? 1.0 : 0.0, 0.0);
}

__global__ void zmatmul(const double2* __restrict__ A, const double2* __restrict__ Bm,
                        double2* __restrict__ C, double alpha, double beta, int transA)
{
    int t = blockIdx.x * 256 + threadIdx.x;
    if (t >= NMODES * NMODES) return;
    int r = t >> 6, c = t & 63;
    double sr = 0.0, si = 0.0;
    for (int k = 0; k < 64; ++k) {
        double2 av = transA ? A[k * 64 + r] : A[r * 64 + k];
        double2 bv = Bm[k * 64 + c];
        sr += av.x * bv.x - av.y * bv.y;
        si += av.x * bv.y + av.y * bv.x;
    }
    sr *= alpha; si *= alpha;
    if (r == c) sr += beta;
    C[t] = make_double2(sr, si);
}

__global__ void ge_inverse(const double2* __restrict__ M,
                           double2* __restrict__ W, double2* __restrict__ Binv)
{
    int tid = threadIdx.x;
    __shared__ double2 pivrow_s[128];
    __shared__ double2 piv_f[64];
    __shared__ int piv_idx;

    for (int idx = tid; idx < 64 * 128; idx += 256) {
        int r = idx >> 7, c = idx & 127;
        double2 v;
        if (c < 64) {
            double2 m = M[r * 64 + c];
            v.x = ((r == c) ? (1.0 + 1e-8) : 0.0) - m.x;
            v.y = -m.y;
        } else {
            v.x = ((c - 64) == r) ? 1.0 : 0.0;
            v.y = 0.0;
        }
        W[idx] = v;
    }
    __syncthreads();

    for (int i = 0; i < 64; ++i) {
        if (tid < 64) {
            double2 v = W[tid * 128 + i];
            double mag = (tid >= i) ? (v.x * v.x + v.y * v.y) : -1.0;
            int idxr = tid;
            for (int off = 1; off < 64; off <<= 1) {
                double omag = __shfl_xor(mag, off);
                int oidx = __shfl_xor(idxr, off);
                if (omag > mag) { mag = omag; idxr = oidx; }
            }
            if (tid == 0) piv_idx = idxr;
        }
        __syncthreads();
        int p = piv_idx;
        double2 pe = W[p * 128 + i];
        double den = pe.x * pe.x + pe.y * pe.y;
        double ipr = pe.x / den, ipi = -pe.y / den;
        __syncthreads();
        if (tid < 128) {
            int c = tid;
            double2 wi = W[i * 128 + c];
            double2 wp = W[p * 128 + c];
            double2 nr;
            nr.x = wp.x * ipr - wp.y * ipi;
            nr.y = wp.x * ipi + wp.y * ipr;
            W[i * 128 + c] = nr;
            if (p != i) W[p * 128 + c] = wi;
            pivrow_s[c] = nr;
        }
        __syncthreads();
        if (tid < 64) piv_f[tid] = W[tid * 128 + i];
        __syncthreads();
        for (int idx = tid; idx < 64 * 128; idx += 256) {
            int r = idx >> 7, c = idx & 127;
            if (r == i) continue;
            double2 f = piv_f[r];
            double2 pr = pivrow_s[c];
            double2 w = W[idx];
            w.x -= f.x * pr.x - f.y * pr.y;
            w.y -= f.x * pr.y + f.y * pr.x;
            W[idx] = w;
        }
        __syncthreads();
    }
    for (int idx = tid; idx < 64 * 64; idx += 256) {
        int r = idx >> 6, c = idx & 63;
        Binv[idx] = W[r * 128 + 64 + c];
    }
}

__global__ void t2_build(const double2* __restrict__ P, const float* __restrict__ kappa,
                         float2* __restrict__ T2c)
{
    int t = blockIdx.x * 256 + threadIdx.x;
    if (t >= NMODES * NMODES) return;
    int r = t >> 6, c = t & 63;
    double2 p = P[t];
    double kc = (double)kappa[c];
    T2c[t] = make_float2((float)(-kc * (p.x + ((r == c) ? 0.5 : 0.0))),
                         (float)(-kc * p.y));
}

// ---------------------------------------------------------------------------
// ODE kernel: one batch element per BLOCK (4 waves); lane j = mode j in every
// wave; wave w owns T2 columns [16w, 16w+16). Partials combined through
// double-buffered LDS in a FIXED order so all 4 waves stay bitwise identical
// (required: they share barriers inside data-dependent control flow).
// ---------------------------------------------------------------------------

__device__ __forceinline__ v2f vfma(float c, v2f a, v2f b) {
    v2f cc = {c, c};
    return __builtin_elementwise_fma(cc, a, b);
}
__device__ __forceinline__ v2f vscale(float c, v2f a) {
    v2f cc = {c, c};
    return cc * a;
}

// full-wave (64-lane) sum via DPP, broadcast via readlane 63
__device__ __forceinline__ float wave_sum64(float x) {
    x += __int_as_float(__builtin_amdgcn_update_dpp(0, __float_as_int(x), 0x111, 0xf, 0xf, false)); // row_shr:1
    x += __int_as_float(__builtin_amdgcn_update_dpp(0, __float_as_int(x), 0x112, 0xf, 0xf, false)); // row_shr:2
    x += __int_as_float(__builtin_amdgcn_update_dpp(0, __float_as_int(x), 0x114, 0xf, 0xf, false)); // row_shr:4
    x += __int_as_float(__builtin_amdgcn_update_dpp(0, __float_as_int(x), 0x118, 0xf, 0xf, false)); // row_shr:8
    x += __int_as_float(__builtin_amdgcn_update_dpp(0, __float_as_int(x), 0x142, 0xa, 0xf, false)); // row_bcast:15
    x += __int_as_float(__builtin_amdgcn_update_dpp(0, __float_as_int(x), 0x143, 0xc, 0xf, false)); // row_bcast:31
    return __int_as_float(__builtin_amdgcn_readlane(__float_as_int(x), 63));
}

// K = (T2 @ Y) + i*(om + nl*|Y|^2)*Y ; this wave contributes 16 columns,
// partials exchanged via LDS buffer BUF (compile-time 0/1).
#define RHS(BUF, Yv, Kv) do {                                                     \
    v2f Pp = {0.f, 0.f}, Qp = {0.f, 0.f};                                         \
    _Pragma("unroll")                                                             \
    for (int q = 0; q < KC; ++q) {                                                \
        float br = __int_as_float(__builtin_amdgcn_readlane(__float_as_int((Yv).x), kbase + q)); \
        float bi = __int_as_float(__builtin_amdgcn_readlane(__float_as_int((Yv).y), kbase + q)); \
        v2f t2p = t2c[q];                                                         \
        v2f brv = {br, br};                                                       \
        v2f biv = {bi, bi};                                                       \
        Pp = __builtin_elementwise_fma(brv, t2p, Pp);                             \
        Qp = __builtin_elementwise_fma(biv, t2p, Qp);                             \
    }                                                                             \
    part[BUF][w][j] = make_float4(Pp.x, Pp.y, Qp.x, Qp.y);                        \
    __syncthreads();                                                              \
    float4 p0 = part[BUF][0][j];                                                  \
    float4 p1 = part[BUF][1][j];                                                  \
    float4 p2 = part[BUF][2][j];                                                  \
    float4 p3 = part[BUF][3][j];                                                  \
    float Px = (p0.x + p1.x) + (p2.x + p3.x);                                     \
    float Py = (p0.y + p1.y) + (p2.y + p3.y);                                     \
    float Qx = (p0.z + p1.z) + (p2.z + p3.z);                                     \
    float Qy = (p0.w + p1.w) + (p2.w + p3.w);                                     \
    float fq = fmaf(nlj, fmaf((Yv).x, (Yv).x, (Yv).y * (Yv).y), om);              \
    (Kv).x = Px - Qy - fq * (Yv).y;                                               \
    (Kv).y = Py + Qx + fq * (Yv).x;                                               \
} while (0)

__global__ void __launch_bounds__(256, 4)
ode_kernel(const float* __restrict__ A0, const float2* __restrict__ T2c,
           const float* __restrict__ omega, const float* __restrict__ nonlin,
           float2* __restrict__ out)
{
    const int b   = blockIdx.x;
    const int tid = threadIdx.x;
    const int j   = tid & 63;
    const int w   = __builtin_amdgcn_readfirstlane(tid >> 6);
    const int kbase = w * KC;

    __shared__ float4 part[2][WS][64];

    v2f t2c[KC];
    const float4* T2v = (const float4*)(T2c + j * 64 + kbase);
#pragma unroll
    for (int k = 0; k < KC / 2; ++k) {
        float4 v = T2v[k];
        t2c[2 * k]     = (v2f){v.x, v.y};
        t2c[2 * k + 1] = (v2f){v.z, v.w};
    }

    const float om  = omega[j];
    const float nlj = nonlin[j];

    v2f Y;
    if (j < 48) {
        Y.x = A0[(b * 48 + j) * 2 + 0];
        Y.y = A0[(b * 48 + j) * 2 + 1];
    } else {
        Y.x = 1.0f; Y.y = 0.0f;
    }

    if (w == 0) out[(size_t)b * 64 + j] = make_float2(Y.x, Y.y);   // t = 0

    const float A21 = 0.2f;
    const float A31 = 3.0f/40.0f, A32 = 9.0f/40.0f;
    const float A41 = 44.0f/45.0f, A42 = -56.0f/15.0f, A43 = 32.0f/9.0f;
    const float A51 = 19372.0f/6561.0f, A52 = -25360.0f/2187.0f,
                A53 = 64448.0f/6561.0f, A54 = -212.0f/729.0f;
    const float A61 = 9017.0f/3168.0f, A62 = -355.0f/33.0f,
                A63 = 46732.0f/5247.0f, A64 = 49.0f/176.0f, A65 = -5103.0f/18656.0f;
    const float B1 = 35.0f/384.0f, B3 = 500.0f/1113.0f, B4 = 125.0f/192.0f,
                B5 = -2187.0f/6784.0f, B6 = 11.0f/84.0f;
    const float E1 = (float)(35.0/384.0 - 5179.0/57600.0);
    const float E3 = (float)(500.0/1113.0 - 7571.0/16695.0);
    const float E4 = (float)(125.0/192.0 - 393.0/640.0);
    const float E5 = (float)(-2187.0/6784.0 + 92097.0/339200.0);
    const float E6 = (float)(11.0/84.0 - 187.0/2100.0);
    const float E7 = (float)(-1.0/40.0);

    v2f K1, K2, K3, K4, K5, K6, K7;

    RHS(0, Y, K1);   // FSAL seed

    float h = 3e-4f;
    const float DT = (float)(2.0 / 199.0);
    const float RTOL = 1e-6f, ATOL = 1e-9f;

    for (int i = 1; i < NEVAL; ++i) {
        float rem = DT;
        while (rem > 0.0f) {
            float hh = fminf(h, rem);

            v2f y2 = vfma(hh * A21, K1, Y);
            RHS(1, y2, K2);

            v2f s3 = vfma(A32, K2, vscale(A31, K1));
            v2f y3 = vfma(hh, s3, Y);
            RHS(0, y3, K3);

            v2f s4 = vfma(A43, K3, vfma(A42, K2, vscale(A41, K1)));
            v2f y4 = vfma(hh, s4, Y);
            RHS(1, y4, K4);

            v2f s5 = vfma(A54, K4, vfma(A53, K3, vfma(A52, K2, vscale(A51, K1))));
            v2f y5 = vfma(hh, s5, Y);
            RHS(0, y5, K5);

            v2f s6 = vfma(A65, K5, vfma(A64, K4, vfma(A63, K3, vfma(A62, K2, vscale(A61, K1)))));
            v2f y6 = vfma(hh, s6, Y);
            RHS(1, y6, K6);

            v2f sn = vfma(B6, K6, vfma(B5, K5, vfma(B4, K4, vfma(B3, K3, vscale(B1, K1)))));
            v2f Yn = vfma(hh, sn, Y);
            RHS(0, Yn, K7);

            v2f se = vfma(E7, K7, vfma(E6, K6, vfma(E5, K5, vfma(E4, K4, vfma(E3, K3, vscale(E1, K1))))));
            v2f E = vscale(hh, se);

            float s0 = fmaf(RTOL, fmaxf(fabsf(Y.x), fabsf(Yn.x)), ATOL);
            float s1 = fmaf(RTOL, fmaxf(fabsf(Y.y), fabsf(Yn.y)), ATOL);
            float q0 = E.x / s0, q1 = E.y / s1;
            float rr = fmaf(q0, q0, q1 * q1);
            float tot = wave_sum64(rr);
            float msq = tot * (1.0f / 128.0f);

            bool accept = (msq <= 1.0f) || (hh <= 1e-6f);
            float rn  = sqrtf(fmaxf(msq, 1e-16f));
            float fac = 0.9f * __powf(rn, -0.2f);
            fac = fminf(fmaxf(fac, 0.2f), 10.0f);
            float hnew = hh * fac;
            if (accept) {
                Y = Yn;
                K1 = K7;                       // FSAL
                rem -= hh;
                if (hh < h) hnew = fmaxf(hnew, h);   // boundary clamp shouldn't shrink h
            }
            h = hnew;
        }
        if (w == 0) out[((size_t)i * BATCHN + b) * 64 + j] = make_float2(Y.x, Y.y);
    }
}

extern "C" void kernel_launch(void* const* d_in, const int* in_sizes, int n_in,
                              void* d_out, int out_size, void* d_ws, size_t ws_size,
                              hipStream_t stream)
{
    const float* A0     = (const float*)d_in[0];
    const float* params = (const float*)d_in[1];
    const float* omega  = (const float*)d_in[2];
    const float* kappa  = (const float*)d_in[3];
    const float* nonlin = (const float*)d_in[4];
    float2* out = (float2*)d_out;

    char* ws = (char*)d_ws;
    double2* X    = (double2*)(ws + 0);
    double2* Ta   = (double2*)(ws + 65536);
    double2* Tb   = (double2*)(ws + 131072);
    double2* W    = (double2*)(ws + 196608);
    double2* Binv = (double2*)(ws + 327680);
    float2*  T2c  = (float2*)(ws + 393216);

    build_kernel<<<16, 256, 0, stream>>>(params, X, Ta, 1.0 / 1024.0);

    double2* cur = Ta; double2* nxt = Tb;
    for (int k = TAYLOR_K; k >= 1; --k) {
        zmatmul<<<16, 256, 0, stream>>>(X, cur, nxt, 1.0 / (double)k, 1.0, 0);
        double2* tmp = cur; cur = nxt; nxt = tmp;
    }
    for (int q = 0; q < SQUARINGS; ++q) {
        zmatmul<<<16, 256, 0, stream>>>(cur, cur, nxt, 1.0, 0.0, 0);
        double2* tmp = cur; cur = nxt; nxt = tmp;
    }
    zmatmul<<<16, 256, 0, stream>>>(cur, cur, nxt, 1.0, 0.0, 1);   // M = U^T U
    ge_inverse<<<1, 256, 0, stream>>>(nxt, W, Binv);
    zmatmul<<<16, 256, 0, stream>>>(nxt, Binv, cur, 1.0, 0.0, 0);  // P = M * Binv
    t2_build<<<16, 256, 0, stream>>>(cur, kappa, T2c);

    ode_kernel<<<BATCHN, 256, 0, stream>>>(A0, T2c, omega, nonlin, out);
}

// Round 5
// 5739.393 us; speedup vs baseline: 1.4485x; 1.4485x over previous
//
#include <hip/hip_runtime.h>

#define NMODES   64
#define NOFF     2016     // 64*63/2
#define BATCHN   1024
#define NEVAL    200
#define TAYLOR_K 12
#define SQUARINGS 10

typedef float v2f __attribute__((ext_vector_type(2)));

// ---------------------------------------------------------------------------
// ws layout (bytes):
//   X    @ 0        : 64*64 double2 = 65536   (X = i*H/2^s)
//   Ta   @ 65536    : 65536                   (ping)
//   Tb   @ 131072   : 65536                   (pong)
//   W    @ 196608   : 64*128 double2 = 131072 (Gauss-Jordan augmented)
//   Binv @ 327680   : 65536
//   T2c  @ 393216   : 64*64 float2 = 32768    (final fp32 T2)
// ---------------------------------------------------------------------------

__global__ void build_kernel(const float* __restrict__ params,
                             double2* __restrict__ X, double2* __restrict__ T,
                             double inv2s)
{
    int t = blockIdx.x * 256 + threadIdx.x;
    if (t >= NMODES * NMODES) return;
    int r = t >> 6, c = t & 63;
    double hre, him;
    if (r < c) {
        int idx = r * 63 - (r * (r - 1)) / 2 + (c - r - 1);
        hre = (double)params[idx];
        him = (double)params[NOFF + idx];
    } else if (r > c) {
        int idx = c * 63 - (c * (c - 1)) / 2 + (r - c - 1);
        hre = (double)params[idx];
        him = -(double)params[NOFF + idx];
    } else {
        him = 0.0;
        if (r < 63) {
            hre = (double)params[2 * NOFF + r];
        } else {
            double s = 0.0;
            for (int q = 0; q < 63; ++q) s += (double)params[2 * NOFF + q];
            hre = -s;
        }
    }
    X[t] = make_double2(-him * inv2s, hre * inv2s);
    T[t] = make_double2((r == c) ? 1.0 : 0.0, 0.0);
}

__global__ void zmatmul(const double2* __restrict__ A, const double2* __restrict__ Bm,
                        double2* __restrict__ C, double alpha, double beta, int transA)
{
    int t = blockIdx.x * 256 + threadIdx.x;
    if (t >= NMODES * NMODES) return;
    int r = t >> 6, c = t & 63;
    double sr = 0.0, si = 0.0;
    for (int k = 0; k < 64; ++k) {
        double2 av = transA ? A[k * 64 + r] : A[r * 64 + k];
        double2 bv = Bm[k * 64 + c];
        sr += av.x * bv.x - av.y * bv.y;
        si += av.x * bv.y + av.y * bv.x;
    }
    sr *= alpha; si *= alpha;
    if (r == c) sr += beta;
    C[t] = make_double2(sr, si);
}

__global__ void ge_inverse(const double2* __restrict__ M,
                           double2* __restrict__ W, double2* __restrict__ Binv)
{
    int tid = threadIdx.x;
    __shared__ double2 pivrow_s[128];
    __shared__ double2 piv_f[64];
    __shared__ int piv_idx;

    for (int idx = tid; idx < 64 * 128; idx += 256) {
        int r = idx >> 7, c = idx & 127;
        double2 v;
        if (c < 64) {
            double2 m = M[r * 64 + c];
            v.x = ((r == c) ? (1.0 + 1e-8) : 0.0) - m.x;
            v.y = -m.y;
        } else {
            v.x = ((c - 64) == r) ? 1.0 : 0.0;
            v.y = 0.0;
        }
        W[idx] = v;
    }
    __syncthreads();

    for (int i = 0; i < 64; ++i) {
        if (tid < 64) {
            double2 v = W[tid * 128 + i];
            double mag = (tid >= i) ? (v.x * v.x + v.y * v.y) : -1.0;
            int idxr = tid;
            for (int off = 1; off < 64; off <<= 1) {
                double omag = __shfl_xor(mag, off);
                int oidx = __shfl_xor(idxr, off);
                if (omag > mag) { mag = omag; idxr = oidx; }
            }
            if (tid == 0) piv_idx = idxr;
        }
        __syncthreads();
        int p = piv_idx;
        double2 pe = W[p * 128 + i];
        double den = pe.x * pe.x + pe.y * pe.y;
        double ipr = pe.x / den, ipi = -pe.y / den;
        __syncthreads();
        if (tid < 128) {
            int c = tid;
            double2 wi = W[i * 128 + c];
            double2 wp = W[p * 128 + c];
            double2 nr;
            nr.x = wp.x * ipr - wp.y * ipi;
            nr.y = wp.x * ipi + wp.y * ipr;
            W[i * 128 + c] = nr;
            if (p != i) W[p * 128 + c] = wi;
            pivrow_s[c] = nr;
        }
        __syncthreads();
        if (tid < 64) piv_f[tid] = W[tid * 128 + i];
        __syncthreads();
        for (int idx = tid; idx < 64 * 128; idx += 256) {
            int r = idx >> 7, c = idx & 127;
            if (r == i) continue;
            double2 f = piv_f[r];
            double2 pr = pivrow_s[c];
            double2 w = W[idx];
            w.x -= f.x * pr.x - f.y * pr.y;
            w.y -= f.x * pr.y + f.y * pr.x;
            W[idx] = w;
        }
        __syncthreads();
    }
    for (int idx = tid; idx < 64 * 64; idx += 256) {
        int r = idx >> 6, c = idx & 63;
        Binv[idx] = W[r * 128 + 64 + c];
    }
}

__global__ void t2_build(const double2* __restrict__ P, const float* __restrict__ kappa,
                         float2* __restrict__ T2c)
{
    int t = blockIdx.x * 256 + threadIdx.x;
    if (t >= NMODES * NMODES) return;
    int r = t >> 6, c = t & 63;
    double2 p = P[t];
    double kc = (double)kappa[c];
    T2c[t] = make_float2((float)(-kc * (p.x + ((r == c) ? 0.5 : 0.0))),
                         (float)(-kc * p.y));
}

// ---------------------------------------------------------------------------
// ODE kernel: one batch element per 64-lane wave (one wave per block).
// T2 row j PINNED in 128 VGPRs (asm makes values opaque -> no remat/reload).
// Y staged in LDS once per RHS; matvec reads it back as 32 broadcast
// ds_read_b128 (uniform address -> conflict-free). No barriers anywhere.
// ---------------------------------------------------------------------------

__device__ __forceinline__ v2f vfma(float c, v2f a, v2f b) {
    v2f cc = {c, c};
    return __builtin_elementwise_fma(cc, a, b);
}
__device__ __forceinline__ v2f vscale(float c, v2f a) {
    v2f cc = {c, c};
    return cc * a;
}

// full-wave (64-lane) sum via DPP, broadcast via readlane 63
__device__ __forceinline__ float wave_sum64(float x) {
    x += __int_as_float(__builtin_amdgcn_update_dpp(0, __float_as_int(x), 0x111, 0xf, 0xf, false)); // row_shr:1
    x += __int_as_float(__builtin_amdgcn_update_dpp(0, __float_as_int(x), 0x112, 0xf, 0xf, false)); // row_shr:2
    x += __int_as_float(__builtin_amdgcn_update_dpp(0, __float_as_int(x), 0x114, 0xf, 0xf, false)); // row_shr:4
    x += __int_as_float(__builtin_amdgcn_update_dpp(0, __float_as_int(x), 0x118, 0xf, 0xf, false)); // row_shr:8
    x += __int_as_float(__builtin_amdgcn_update_dpp(0, __float_as_int(x), 0x142, 0xa, 0xf, false)); // row_bcast:15
    x += __int_as_float(__builtin_amdgcn_update_dpp(0, __float_as_int(x), 0x143, 0xc, 0xf, false)); // row_bcast:31
    return __int_as_float(__builtin_amdgcn_readlane(__float_as_int(x), 63));
}

// K = (T2 @ Y) + i*(om + nl*|Y|^2)*Y
// Stage Y to LDS buffer BUF, then 32 broadcast b128 reads + 128 pk_fma
// across 4 independent accumulator chains.
#define RHS(BUF, Yv, Kv) do {                                                     \
    sY[BUF][j] = make_float2((Yv).x, (Yv).y);                                     \
    float fq = fmaf(nlj, fmaf((Yv).x, (Yv).x, (Yv).y * (Yv).y), om);              \
    v2f Pa = {0.f, 0.f}, Pb = {0.f, 0.f}, Qa = {0.f, 0.f}, Qb = {0.f, 0.f};       \
    const float4* yv = (const float4*)sY[BUF];                                    \
    _Pragma("unroll")                                                             \
    for (int q = 0; q < 32; ++q) {                                                \
        float4 yp = yv[q];                                                        \
        v2f t0 = t2c[2 * q];                                                      \
        v2f t1 = t2c[2 * q + 1];                                                  \
        v2f v0 = {yp.x, yp.x};                                                    \
        v2f v1 = {yp.y, yp.y};                                                    \
        v2f v2 = {yp.z, yp.z};                                                    \
        v2f v3 = {yp.w, yp.w};                                                    \
        Pa = __builtin_elementwise_fma(v0, t0, Pa);                               \
        Qa = __builtin_elementwise_fma(v1, t0, Qa);                               \
        Pb = __builtin_elementwise_fma(v2, t1, Pb);                               \
        Qb = __builtin_elementwise_fma(v3, t1, Qb);                               \
    }                                                                             \
    v2f P = Pa + Pb;                                                              \
    v2f Q = Qa + Qb;                                                              \
    (Kv).x = P.x - Q.y - fq * (Yv).y;                                             \
    (Kv).y = P.y + Q.x + fq * (Yv).x;                                             \
} while (0)

__global__ void __launch_bounds__(64, 1)
ode_kernel(const float* __restrict__ A0, const float2* __restrict__ T2c,
           const float* __restrict__ omega, const float* __restrict__ nonlin,
           float2* __restrict__ out)
{
    const int b = blockIdx.x;
    const int j = threadIdx.x;

    __shared__ float2 sY[2][64];

    // T2 row j -> 64 x v2f, pinned in VGPRs (opaque to the optimizer)
    v2f t2c[64];
    const float4* T2v = (const float4*)(T2c + j * 64);
#pragma unroll
    for (int k = 0; k < 32; ++k) {
        float4 v = T2v[k];
        t2c[2 * k]     = (v2f){v.x, v.y};
        t2c[2 * k + 1] = (v2f){v.z, v.w};
    }
#pragma unroll
    for (int k = 0; k < 64; ++k) {
        asm volatile("" : "+v"(t2c[k]));
    }

    const float om  = omega[j];
    const float nlj = nonlin[j];

    v2f Y;
    if (j < 48) {
        Y.x = A0[(b * 48 + j) * 2 + 0];
        Y.y = A0[(b * 48 + j) * 2 + 1];
    } else {
        Y.x = 1.0f; Y.y = 0.0f;
    }

    out[(size_t)b * 64 + j] = make_float2(Y.x, Y.y);   // t = 0

    const float A21 = 0.2f;
    const float A31 = 3.0f/40.0f, A32 = 9.0f/40.0f;
    const float A41 = 44.0f/45.0f, A42 = -56.0f/15.0f, A43 = 32.0f/9.0f;
    const float A51 = 19372.0f/6561.0f, A52 = -25360.0f/2187.0f,
                A53 = 64448.0f/6561.0f, A54 = -212.0f/729.0f;
    const float A61 = 9017.0f/3168.0f, A62 = -355.0f/33.0f,
                A63 = 46732.0f/5247.0f, A64 = 49.0f/176.0f, A65 = -5103.0f/18656.0f;
    const float B1 = 35.0f/384.0f, B3 = 500.0f/1113.0f, B4 = 125.0f/192.0f,
                B5 = -2187.0f/6784.0f, B6 = 11.0f/84.0f;
    const float E1 = (float)(35.0/384.0 - 5179.0/57600.0);
    const float E3 = (float)(500.0/1113.0 - 7571.0/16695.0);
    const float E4 = (float)(125.0/192.0 - 393.0/640.0);
    const float E5 = (float)(-2187.0/6784.0 + 92097.0/339200.0);
    const float E6 = (float)(11.0/84.0 - 187.0/2100.0);
    const float E7 = (float)(-1.0/40.0);

    v2f K1, K2, K3, K4, K5, K6, K7;

    RHS(0, Y, K1);   // FSAL seed

    float h = 3e-4f;
    const float DT = (float)(2.0 / 199.0);
    const float RTOL = 1e-6f, ATOL = 1e-9f;

    for (int i = 1; i < NEVAL; ++i) {
        float rem = DT;
        while (rem > 0.0f) {
            float hh = fminf(h, rem);

            v2f y2 = vfma(hh * A21, K1, Y);
            RHS(1, y2, K2);

            v2f s3 = vfma(A32, K2, vscale(A31, K1));
            v2f y3 = vfma(hh, s3, Y);
            RHS(0, y3, K3);

            v2f s4 = vfma(A43, K3, vfma(A42, K2, vscale(A41, K1)));
            v2f y4 = vfma(hh, s4, Y);
            RHS(1, y4, K4);

            v2f s5 = vfma(A54, K4, vfma(A53, K3, vfma(A52, K2, vscale(A51, K1))));
            v2f y5 = vfma(hh, s5, Y);
            RHS(0, y5, K5);

            v2f s6 = vfma(A65, K5, vfma(A64, K4, vfma(A63, K3, vfma(A62, K2, vscale(A61, K1)))));
            v2f y6 = vfma(hh, s6, Y);
            RHS(1, y6, K6);

            v2f sn = vfma(B6, K6, vfma(B5, K5, vfma(B4, K4, vfma(B3, K3, vscale(B1, K1)))));
            v2f Yn = vfma(hh, sn, Y);
            RHS(0, Yn, K7);

            v2f se = vfma(E7, K7, vfma(E6, K6, vfma(E5, K5, vfma(E4, K4, vfma(E3, K3, vscale(E1, K1))))));
            v2f E = vscale(hh, se);

            float s0 = fmaf(RTOL, fmaxf(fabsf(Y.x), fabsf(Yn.x)), ATOL);
            float s1 = fmaf(RTOL, fmaxf(fabsf(Y.y), fabsf(Yn.y)), ATOL);
            float q0 = E.x / s0, q1 = E.y / s1;
            float rr = fmaf(q0, q0, q1 * q1);
            float tot = wave_sum64(rr);
            float msq = tot * (1.0f / 128.0f);

            bool accept = (msq <= 1.0f) || (hh <= 1e-6f);
            float rn  = sqrtf(fmaxf(msq, 1e-16f));
            float fac = 0.9f * __powf(rn, -0.2f);
            fac = fminf(fmaxf(fac, 0.2f), 10.0f);
            float hnew = hh * fac;
            if (accept) {
                Y = Yn;
                K1 = K7;                       // FSAL
                rem -= hh;
                if (hh < h) hnew = fmaxf(hnew, h);   // boundary clamp shouldn't shrink h
            }
            h = hnew;
        }
        out[((size_t)i * BATCHN + b) * 64 + j] = make_float2(Y.x, Y.y);
    }
}

extern "C" void kernel_launch(void* const* d_in, const int* in_sizes, int n_in,
                              void* d_out, int out_size, void* d_ws, size_t ws_size,
                              hipStream_t stream)
{
    const float* A0     = (const float*)d_in[0];
    const float* params = (const float*)d_in[1];
    const float* omega  = (const float*)d_in[2];
    const float* kappa  = (const float*)d_in[3];
    const float* nonlin = (const float*)d_in[4];
    float2* out = (float2*)d_out;

    char* ws = (char*)d_ws;
    double2* X    = (double2*)(ws + 0);
    double2* Ta   = (double2*)(ws + 65536);
    double2* Tb   = (double2*)(ws + 131072);
    double2* W    = (double2*)(ws + 196608);
    double2* Binv = (double2*)(ws + 327680);
    float2*  T2c  = (float2*)(ws + 393216);

    build_kernel<<<16, 256, 0, stream>>>(params, X, Ta, 1.0 / 1024.0);

    double2* cur = Ta; double2* nxt = Tb;
    for (int k = TAYLOR_K; k >= 1; --k) {
        zmatmul<<<16, 256, 0, stream>>>(X, cur, nxt, 1.0 / (double)k, 1.0, 0);
        double2* tmp = cur; cur = nxt; nxt = tmp;
    }
    for (int q = 0; q < SQUARINGS; ++q) {
        zmatmul<<<16, 256, 0, stream>>>(cur, cur, nxt, 1.0, 0.0, 0);
        double2* tmp = cur; cur = nxt; nxt = tmp;
    }
    zmatmul<<<16, 256, 0, stream>>>(cur, cur, nxt, 1.0, 0.0, 1);   // M = U^T U
    ge_inverse<<<1, 256, 0, stream>>>(nxt, W, Binv);
    zmatmul<<<16, 256, 0, stream>>>(nxt, Binv, cur, 1.0, 0.0, 0);  // P = M * Binv
    t2_build<<<16, 256, 0, stream>>>(cur, kappa, T2c);

    ode_kernel<<<BATCHN, 64, 0, stream>>>(A0, T2c, omega, nonlin, out);
}

// Round 6
// 2380.322 us; speedup vs baseline: 3.4926x; 2.4112x over previous
//
#include <hip/hip_runtime.h>

#define NMODES   64
#define NOFF     2016     // 64*63/2
#define BATCHN   1024
#define NEVAL    200
#define TAYLOR_K 12
#define SQUARINGS 10
#define NSUB     16       // substeps per output interval (split-step)

typedef float v2f __attribute__((ext_vector_type(2)));

// ---------------------------------------------------------------------------
// ws layout (bytes):
//   X    @ 0        : 64*64 double2 = 65536
//   Ta   @ 65536    : 65536   (ping)
//   Tb   @ 131072   : 65536   (pong)
//   W    @ 196608   : 131072  (Gauss-Jordan augmented; later reused for Xe)
//   Binv @ 327680   : 65536
//   Ec   @ 393216   : 32768   (final fp32 propagator E = expm(h*L))
// ---------------------------------------------------------------------------

__global__ void build_kernel(const float* __restrict__ params,
                             double2* __restrict__ X, double2* __restrict__ T,
                             double inv2s)
{
    int t = blockIdx.x * 256 + threadIdx.x;
    if (t >= NMODES * NMODES) return;
    int r = t >> 6, c = t & 63;
    double hre, him;
    if (r < c) {
        int idx = r * 63 - (r * (r - 1)) / 2 + (c - r - 1);
        hre = (double)params[idx];
        him = (double)params[NOFF + idx];
    } else if (r > c) {
        int idx = c * 63 - (c * (c - 1)) / 2 + (r - c - 1);
        hre = (double)params[idx];
        him = -(double)params[NOFF + idx];
    } else {
        him = 0.0;
        if (r < 63) {
            hre = (double)params[2 * NOFF + r];
        } else {
            double s = 0.0;
            for (int q = 0; q < 63; ++q) s += (double)params[2 * NOFF + q];
            hre = -s;
        }
    }
    X[t] = make_double2(-him * inv2s, hre * inv2s);
    T[t] = make_double2((r == c) ? 1.0 : 0.0, 0.0);
}

// C = alpha*(opA(A) @ B) + beta*I      (complex fp64, 64x64)
__global__ void zmatmul(const double2* __restrict__ A, const double2* __restrict__ Bm,
                        double2* __restrict__ C, double alpha, double beta, int transA)
{
    int t = blockIdx.x * 256 + threadIdx.x;
    if (t >= NMODES * NMODES) return;
    int r = t >> 6, c = t & 63;
    double sr = 0.0, si = 0.0;
    for (int k = 0; k < 64; ++k) {
        double2 av = transA ? A[k * 64 + r] : A[r * 64 + k];
        double2 bv = Bm[k * 64 + c];
        sr += av.x * bv.x - av.y * bv.y;
        si += av.x * bv.y + av.y * bv.x;
    }
    sr *= alpha; si *= alpha;
    if (r == c) sr += beta;
    C[t] = make_double2(sr, si);
}

__global__ void ge_inverse(const double2* __restrict__ M,
                           double2* __restrict__ W, double2* __restrict__ Binv)
{
    int tid = threadIdx.x;
    __shared__ double2 pivrow_s[128];
    __shared__ double2 piv_f[64];
    __shared__ int piv_idx;

    for (int idx = tid; idx < 64 * 128; idx += 256) {
        int r = idx >> 7, c = idx & 127;
        double2 v;
        if (c < 64) {
            double2 m = M[r * 64 + c];
            v.x = ((r == c) ? (1.0 + 1e-8) : 0.0) - m.x;
            v.y = -m.y;
        } else {
            v.x = ((c - 64) == r) ? 1.0 : 0.0;
            v.y = 0.0;
        }
        W[idx] = v;
    }
    __syncthreads();

    for (int i = 0; i < 64; ++i) {
        if (tid < 64) {
            double2 v = W[tid * 128 + i];
            double mag = (tid >= i) ? (v.x * v.x + v.y * v.y) : -1.0;
            int idxr = tid;
            for (int off = 1; off < 64; off <<= 1) {
                double omag = __shfl_xor(mag, off);
                int oidx = __shfl_xor(idxr, off);
                if (omag > mag) { mag = omag; idxr = oidx; }
            }
            if (tid == 0) piv_idx = idxr;
        }
        __syncthreads();
        int p = piv_idx;
        double2 pe = W[p * 128 + i];
        double den = pe.x * pe.x + pe.y * pe.y;
        double ipr = pe.x / den, ipi = -pe.y / den;
        __syncthreads();
        if (tid < 128) {
            int c = tid;
            double2 wi = W[i * 128 + c];
            double2 wp = W[p * 128 + c];
            double2 nr;
            nr.x = wp.x * ipr - wp.y * ipi;
            nr.y = wp.x * ipi + wp.y * ipr;
            W[i * 128 + c] = nr;
            if (p != i) W[p * 128 + c] = wi;
            pivrow_s[c] = nr;
        }
        __syncthreads();
        if (tid < 64) piv_f[tid] = W[tid * 128 + i];
        __syncthreads();
        for (int idx = tid; idx < 64 * 128; idx += 256) {
            int r = idx >> 7, c = idx & 127;
            if (r == i) continue;
            double2 f = piv_f[r];
            double2 pr = pivrow_s[c];
            double2 w = W[idx];
            w.x -= f.x * pr.x - f.y * pr.y;
            w.y -= f.x * pr.y + f.y * pr.x;
            W[idx] = w;
        }
        __syncthreads();
    }
    for (int idx = tid; idx < 64 * 64; idx += 256) {
        int r = idx >> 6, c = idx & 63;
        Binv[idx] = W[r * 128 + 64 + c];
    }
}

// Xe = hq * L, where L = i*diag(omega) + T2, T2[r,c] = -kappa[c]*(P[r,c] + 0.5*d_rc)
// Also seeds T = I for the Horner chain.
__global__ void lh_build(const double2* __restrict__ P, const float* __restrict__ kappa,
                         const float* __restrict__ omega, double hq,
                         double2* __restrict__ Xe, double2* __restrict__ T)
{
    int t = blockIdx.x * 256 + threadIdx.x;
    if (t >= NMODES * NMODES) return;
    int r = t >> 6, c = t & 63;
    double2 p = P[t];
    double kc = (double)kappa[c];
    double t2r = -kc * (p.x + ((r == c) ? 0.5 : 0.0));
    double t2i = -kc * p.y;
    double li = t2i + ((r == c) ? (double)omega[r] : 0.0);
    Xe[t] = make_double2(hq * t2r, hq * li);
    T[t]  = make_double2((r == c) ? 1.0 : 0.0, 0.0);
}

__global__ void ecast(const double2* __restrict__ E, float2* __restrict__ Ec)
{
    int t = blockIdx.x * 256 + threadIdx.x;
    if (t >= NMODES * NMODES) return;
    Ec[t] = make_float2((float)E[t].x, (float)E[t].y);
}

// ---------------------------------------------------------------------------
// Split-step ODE kernel: one batch element per 64-lane wave, lane j = mode j.
// Per substep: exact drift Y <- E*Y (readlane-broadcast matvec, the round-2
// codegen that measured 72% VALUBusy) + nonlinear phase kick
// Y <- exp(i*nl*|Y|^2*tau)*Y (2-term Taylor sin/cos, exact to fp32 ulp for
// the tiny angles involved). Linear oscillations handled EXACTLY by E.
// ---------------------------------------------------------------------------

__device__ __forceinline__ float rl(float x, int k) {
    return __int_as_float(__builtin_amdgcn_readlane(__float_as_int(x), k));
}

#define MATVEC() do {                                                         \
    v2f Pa = {0.f,0.f}, Pb = {0.f,0.f}, Qa = {0.f,0.f}, Qb = {0.f,0.f};       \
    _Pragma("unroll")                                                         \
    for (int kk = 0; kk < 64; kk += 2) {                                      \
        float br0 = rl(Y.x, kk),     bi0 = rl(Y.y, kk);                       \
        float br1 = rl(Y.x, kk + 1), bi1 = rl(Y.y, kk + 1);                   \
        v2f e0 = ec[kk], e1 = ec[kk + 1];                                     \
        Pa = __builtin_elementwise_fma((v2f){br0, br0}, e0, Pa);              \
        Qa = __builtin_elementwise_fma((v2f){bi0, bi0}, e0, Qa);              \
        Pb = __builtin_elementwise_fma((v2f){br1, br1}, e1, Pb);              \
        Qb = __builtin_elementwise_fma((v2f){bi1, bi1}, e1, Qb);              \
    }                                                                         \
    v2f P = Pa + Pb, Q = Qa + Qb;                                             \
    Y.x = P.x - Q.y;                                                          \
    Y.y = P.y + Q.x;                                                          \
} while (0)

// phase kick: Y <- exp(i * nlj * |Y|^2 * TAU) * Y
#define KICK(CNL) do {                                                        \
    float q  = fmaf(Y.x, Y.x, Y.y * Y.y);                                     \
    float th = (CNL) * q;                                                     \
    float t2 = th * th;                                                       \
    float sn = th * fmaf(t2, fmaf(t2, 8.3333333e-3f, -1.6666667e-1f), 1.0f);  \
    float cs = fmaf(t2, fmaf(t2, 4.1666667e-2f, -0.5f), 1.0f);                \
    float yr = cs * Y.x - sn * Y.y;                                           \
    Y.y = fmaf(cs, Y.y, sn * Y.x);                                            \
    Y.x = yr;                                                                 \
} while (0)

__global__ void __launch_bounds__(64, 1)
ode_kernel(const float* __restrict__ A0, const float2* __restrict__ Ec,
           const float* __restrict__ nonlin, float2* __restrict__ out)
{
    const int b = blockIdx.x;
    const int j = threadIdx.x;

    // E row j (round-2 load pattern; no pinning games)
    v2f ec[64];
    const float4* Ev = (const float4*)(Ec + j * 64);
#pragma unroll
    for (int k = 0; k < 32; ++k) {
        float4 v = Ev[k];
        ec[2 * k]     = (v2f){v.x, v.y};
        ec[2 * k + 1] = (v2f){v.z, v.w};
    }

    const float nlj = nonlin[j];
    const float HS  = (float)(2.0 / (199.0 * (double)NSUB));
    const float CNL_FULL = nlj * HS;
    const float CNL_HALF = nlj * (0.5f * HS);

    v2f Y;
    if (j < 48) {
        Y.x = A0[(b * 48 + j) * 2 + 0];
        Y.y = A0[(b * 48 + j) * 2 + 1];
    } else {
        Y.x = 1.0f; Y.y = 0.0f;
    }

    out[(size_t)b * 64 + j] = make_float2(Y.x, Y.y);   // t = 0

    for (int i = 1; i < NEVAL; ++i) {
        KICK(CNL_HALF);
#pragma unroll 1
        for (int s = 0; s < NSUB - 1; ++s) {
            MATVEC();
            KICK(CNL_FULL);
        }
        MATVEC();
        KICK(CNL_HALF);
        out[((size_t)i * BATCHN + b) * 64 + j] = make_float2(Y.x, Y.y);
    }
}

extern "C" void kernel_launch(void* const* d_in, const int* in_sizes, int n_in,
                              void* d_out, int out_size, void* d_ws, size_t ws_size,
                              hipStream_t stream)
{
    const float* A0     = (const float*)d_in[0];
    const float* params = (const float*)d_in[1];
    const float* omega  = (const float*)d_in[2];
    const float* kappa  = (const float*)d_in[3];
    const float* nonlin = (const float*)d_in[4];
    float2* out = (float2*)d_out;

    char* ws = (char*)d_ws;
    double2* X    = (double2*)(ws + 0);
    double2* Ta   = (double2*)(ws + 65536);
    double2* Tb   = (double2*)(ws + 131072);
    double2* W    = (double2*)(ws + 196608);
    double2* Binv = (double2*)(ws + 327680);
    float2*  Ec   = (float2*)(ws + 393216);

    // ---- U = expm(iH) (validated chain) ----
    build_kernel<<<16, 256, 0, stream>>>(params, X, Ta, 1.0 / 1024.0);
    double2* cur = Ta; double2* nxt = Tb;
    for (int k = TAYLOR_K; k >= 1; --k) {
        zmatmul<<<16, 256, 0, stream>>>(X, cur, nxt, 1.0 / (double)k, 1.0, 0);
        double2* tmp = cur; cur = nxt; nxt = tmp;
    }
    for (int q = 0; q < SQUARINGS; ++q) {
        zmatmul<<<16, 256, 0, stream>>>(cur, cur, nxt, 1.0, 0.0, 0);
        double2* tmp = cur; cur = nxt; nxt = tmp;
    }
    // cur == Ta holds U
    zmatmul<<<16, 256, 0, stream>>>(cur, cur, nxt, 1.0, 0.0, 1);   // M = U^T U -> Tb
    ge_inverse<<<1, 256, 0, stream>>>(nxt, W, Binv);               // Binv = (I-M+eps I)^-1
    zmatmul<<<16, 256, 0, stream>>>(nxt, Binv, X, 1.0, 0.0, 0);    // P = M*Binv -> X

    // ---- E = expm(h*L), h = DT/NSUB, via Taylor(12) on (h/4)L + 2 squarings ----
    double hq = (2.0 / (199.0 * (double)NSUB)) * 0.25;
    lh_build<<<16, 256, 0, stream>>>(X, kappa, omega, hq, W, Ta);  // Xe->W, I->Ta
    cur = Ta; nxt = Tb;
    for (int k = TAYLOR_K; k >= 1; --k) {
        zmatmul<<<16, 256, 0, stream>>>(W, cur, nxt, 1.0 / (double)k, 1.0, 0);
        double2* tmp = cur; cur = nxt; nxt = tmp;
    }
    for (int q = 0; q < 2; ++q) {
        zmatmul<<<16, 256, 0, stream>>>(cur, cur, nxt, 1.0, 0.0, 0);
        double2* tmp = cur; cur = nxt; nxt = tmp;
    }
    // cur == Ta holds E
    ecast<<<16, 256, 0, stream>>>(cur, Ec);

    // ---- split-step integration ----
    ode_kernel<<<BATCHN, 64, 0, stream>>>(A0, Ec, nonlin, out);
}